// Round 7
// baseline (239.898 us; speedup 1.0000x reference)
//
#include <hip/hip_runtime.h>
#include <hip/hip_fp16.h>

#define D 64
#define SZ 512           // nodes per radix bucket (dst>>9 / src>>9)
#define EPB 2048         // edges per scatter block (8/thread, register-held)
#define CAPB 8192        // slots per bucket region; Binom(1e6,1/196) max ~5500 << 8192
// Assumes N <= 131072 (src fits 17 bits, nb <= 256). Harness: N=100000, E=1000000.

static __device__ __forceinline__ __half2 u2h2(unsigned u) {
    union { unsigned u; __half2 h; } c; c.u = u; return c.h;
}
static __device__ __forceinline__ unsigned h22u(__half2 h) {
    union { __half2 h; unsigned u; } c; c.h = h; return c.u;
}

// ---------------- A: bucket-partition edges. 8 edges/thread in REGISTERS (no LDS
// stash -> 6KB LDS, 8 blocks/CU), int4-vectorized edge loads. Global atomics only
// at reserve: 2 per (block,bucket). Bucket b owns [b*CAPB, (b+1)*CAPB).
__global__ __launch_bounds__(256) void scatter_kernel(
    const int* __restrict__ src, const int* __restrict__ dst,
    int* __restrict__ gcntD, int* __restrict__ gcntS,
    unsigned* __restrict__ packD, unsigned short* __restrict__ packS,
    int E, int nb) {
    int tid = threadIdx.x;
    __shared__ int hD[256], hS[256], baseD[256], baseS[256], curD[256], curS[256];
    hD[tid] = 0; hS[tid] = 0; curD[tid] = 0; curS[tid] = 0;
    __syncthreads();
    int base = (int)blockIdx.x * EPB + 8 * tid;
    int s0,s1,s2,s3,s4,s5,s6,s7, d0,d1,d2,d3,d4,d5,d6,d7;
    if (base + 8 <= E) {
        int4 a = *(const int4*)&src[base], b = *(const int4*)&src[base + 4];
        s0=a.x; s1=a.y; s2=a.z; s3=a.w; s4=b.x; s5=b.y; s6=b.z; s7=b.w;
        a = *(const int4*)&dst[base]; b = *(const int4*)&dst[base + 4];
        d0=a.x; d1=a.y; d2=a.z; d3=a.w; d4=b.x; d5=b.y; d6=b.z; d7=b.w;
    } else {
        s0=s1=s2=s3=s4=s5=s6=s7=-1; d0=d1=d2=d3=d4=d5=d6=d7=0;
        if (base + 0 < E) { s0 = src[base + 0]; d0 = dst[base + 0]; }
        if (base + 1 < E) { s1 = src[base + 1]; d1 = dst[base + 1]; }
        if (base + 2 < E) { s2 = src[base + 2]; d2 = dst[base + 2]; }
        if (base + 3 < E) { s3 = src[base + 3]; d3 = dst[base + 3]; }
        if (base + 4 < E) { s4 = src[base + 4]; d4 = dst[base + 4]; }
        if (base + 5 < E) { s5 = src[base + 5]; d5 = dst[base + 5]; }
        if (base + 6 < E) { s6 = src[base + 6]; d6 = dst[base + 6]; }
        if (base + 7 < E) { s7 = src[base + 7]; d7 = dst[base + 7]; }
    }
#define HIST(S, Dd) if (S >= 0) { atomicAdd(&hD[Dd >> 9], 1); atomicAdd(&hS[S >> 9], 1); }
    HIST(s0,d0) HIST(s1,d1) HIST(s2,d2) HIST(s3,d3)
    HIST(s4,d4) HIST(s5,d5) HIST(s6,d6) HIST(s7,d7)
#undef HIST
    __syncthreads();
    if (tid < nb) {
        int c = hD[tid];
        baseD[tid] = tid * CAPB + (c ? atomicAdd(&gcntD[tid], c) : 0);
        c = hS[tid];
        baseS[tid] = tid * CAPB + (c ? atomicAdd(&gcntS[tid], c) : 0);
    }
    __syncthreads();
#define SCAT(S, Dd) if (S >= 0) { \
        int bd = Dd >> 9, bs_ = S >> 9; \
        int ld = atomicAdd(&curD[bd], 1); \
        int ls = atomicAdd(&curS[bs_], 1); \
        packD[baseD[bd] + ld] = ((unsigned)S << 9) | (unsigned)(Dd & 511); \
        packS[baseS[bs_] + ls] = (unsigned short)(S & 511); }
    SCAT(s0,d0) SCAT(s1,d1) SCAT(s2,d2) SCAT(s3,d3)
    SCAT(s4,d4) SCAT(s5,d5) SCAT(s6,d6) SCAT(s7,d7)
#undef SCAT
}

// ---------------- B: per-bucket CSR build + norms (uint4-vectorized passes) --------
// Blocks [0,nb): dst role -> rowbeg/rowend, csr, in_norm. Blocks [nb,2nb): out_norm.
__global__ __launch_bounds__(256) void build_kernel(
    const unsigned* __restrict__ packD, const unsigned short* __restrict__ packS,
    const int* __restrict__ gcntD, const int* __restrict__ gcntS,
    int* __restrict__ csr, int* __restrict__ rowbeg, int* __restrict__ rowend,
    float* __restrict__ in_norm, float* __restrict__ out_norm,
    int n, int nb) {
    int tid = threadIdx.x;
    __shared__ int cnt[512], lptr[512], tmp[256];
    bool roleD = ((int)blockIdx.x < nb);
    int b = roleD ? (int)blockIdx.x : (int)blockIdx.x - nb;
    int bs = b * CAPB;
    int be = bs + (roleD ? gcntD[b] : gcntS[b]);
    cnt[tid] = 0; cnt[tid + 256] = 0;
    __syncthreads();
    if (roleD) {
        for (int i = bs + 4 * tid; i < be; i += 1024) {
            if (i + 4 <= be) {
                uint4 p = *(const uint4*)&packD[i];
                atomicAdd(&cnt[p.x & 511], 1); atomicAdd(&cnt[p.y & 511], 1);
                atomicAdd(&cnt[p.z & 511], 1); atomicAdd(&cnt[p.w & 511], 1);
            } else {
                for (int q = i; q < be; q++) atomicAdd(&cnt[packD[q] & 511], 1);
            }
        }
        __syncthreads();
        // exclusive scan over 512 node counts (pair trick with 256 threads)
        int a0 = cnt[2 * tid], a1 = cnt[2 * tid + 1];
        tmp[tid] = a0 + a1; __syncthreads();
        for (int off = 1; off < 256; off <<= 1) {
            int u = (tid >= off) ? tmp[tid - off] : 0; __syncthreads();
            tmp[tid] += u; __syncthreads();
        }
        int ex = tmp[tid] - (a0 + a1);
        lptr[2 * tid] = ex; lptr[2 * tid + 1] = ex + a0;
        __syncthreads();
        int v0 = b * SZ + tid, v1 = v0 + 256;
        if (v0 < n) {
            rowbeg[v0] = bs + lptr[tid];
            rowend[v0] = bs + lptr[tid] + cnt[tid];
            in_norm[v0] = rsqrtf((float)max(cnt[tid], 1));
        }
        if (v1 < n) {
            rowbeg[v1] = bs + lptr[tid + 256];
            rowend[v1] = bs + lptr[tid + 256] + cnt[tid + 256];
            in_norm[v1] = rsqrtf((float)max(cnt[tid + 256], 1));
        }
        __syncthreads();
        // fill packed CSR: slots via LDS cursor (lptr consumed)
        for (int i = bs + 4 * tid; i < be; i += 1024) {
            if (i + 4 <= be) {
                uint4 p = *(const uint4*)&packD[i];
                int sl;
                sl = atomicAdd(&lptr[p.x & 511], 1); csr[bs + sl] = (int)(p.x >> 9);
                sl = atomicAdd(&lptr[p.y & 511], 1); csr[bs + sl] = (int)(p.y >> 9);
                sl = atomicAdd(&lptr[p.z & 511], 1); csr[bs + sl] = (int)(p.z >> 9);
                sl = atomicAdd(&lptr[p.w & 511], 1); csr[bs + sl] = (int)(p.w >> 9);
            } else {
                for (int q = i; q < be; q++) {
                    unsigned p = packD[q];
                    int sl = atomicAdd(&lptr[p & 511], 1);
                    csr[bs + sl] = (int)(p >> 9);
                }
            }
        }
    } else {
        for (int i = bs + 8 * tid; i < be; i += 2048) {
            if (i + 8 <= be) {
                uint4 p = *(const uint4*)&packS[i];     // 8 ushorts
                atomicAdd(&cnt[p.x & 0xFFFF], 1); atomicAdd(&cnt[p.x >> 16], 1);
                atomicAdd(&cnt[p.y & 0xFFFF], 1); atomicAdd(&cnt[p.y >> 16], 1);
                atomicAdd(&cnt[p.z & 0xFFFF], 1); atomicAdd(&cnt[p.z >> 16], 1);
                atomicAdd(&cnt[p.w & 0xFFFF], 1); atomicAdd(&cnt[p.w >> 16], 1);
            } else {
                for (int q = i; q < be; q++) atomicAdd(&cnt[packS[q]], 1);
            }
        }
        __syncthreads();
        int v0 = b * SZ + tid, v1 = v0 + 256;
        if (v0 < n) out_norm[v0] = rsqrtf((float)max(cnt[tid], 1));
        if (v1 < n) out_norm[v1] = rsqrtf((float)max(cnt[tid + 256], 1));
    }
}

// ---------------- GEMM: Y = half(scale * (X @ W)), 64x64 LDS tile, 4x4/thread -------
// Xs: 16B-chunk XOR swizzle (chunk kq of row r at Xs[r*64 + ((kq^(r&15))<<2)]).
// __launch_bounds__(256,4): cap VGPR (round-2 lesson: uncapped -> 244 VGPR, 9% occ).
__global__ __launch_bounds__(256, 4) void gemm_kernel(
    const float* __restrict__ X, const float* __restrict__ W,
    const float* __restrict__ scale, __half* __restrict__ P, int n) {
    __shared__ float Ws[64 * 64];
    __shared__ float Xs[64 * 64];
    int tid = threadIdx.x;
    int row0 = (int)blockIdx.x * 64;
    if (row0 >= n) return;
    {
        const float4* W4 = (const float4*)W;
        float4* Ws4 = (float4*)Ws;
#pragma unroll
        for (int i = 0; i < 4; i++) Ws4[tid + 256 * i] = W4[tid + 256 * i];
    }
    {
#pragma unroll
        for (int i = 0; i < 4; i++) {
            int idx = tid + 256 * i;          // 0..1023 = 64 rows x 16 chunks
            int r = idx >> 4, kq = idx & 15;
            float4 v = make_float4(0.f, 0.f, 0.f, 0.f);
            int row = row0 + r;
            if (row < n) v = ((const float4*)X)[(size_t)row * 16 + kq];
            *(float4*)&Xs[r * 64 + ((kq ^ (r & 15)) << 2)] = v;
        }
    }
    __syncthreads();

    int tx = tid & 15, ty = tid >> 4;
    float acc[4][4] = {};
#pragma unroll 4
    for (int kc = 0; kc < 16; kc++) {
        float4 wv[4];
#pragma unroll
        for (int j = 0; j < 4; j++) wv[j] = *(float4*)&Ws[(4 * kc + j) * 64 + 4 * tx];
#pragma unroll
        for (int r = 0; r < 4; r++) {
            int row = 4 * ty + r;
            float4 xv = *(float4*)&Xs[row * 64 + ((kc ^ (row & 15)) << 2)];
            acc[r][0] = fmaf(xv.x, wv[0].x, acc[r][0]);
            acc[r][1] = fmaf(xv.x, wv[0].y, acc[r][1]);
            acc[r][2] = fmaf(xv.x, wv[0].z, acc[r][2]);
            acc[r][3] = fmaf(xv.x, wv[0].w, acc[r][3]);
            acc[r][0] = fmaf(xv.y, wv[1].x, acc[r][0]);
            acc[r][1] = fmaf(xv.y, wv[1].y, acc[r][1]);
            acc[r][2] = fmaf(xv.y, wv[1].z, acc[r][2]);
            acc[r][3] = fmaf(xv.y, wv[1].w, acc[r][3]);
            acc[r][0] = fmaf(xv.z, wv[2].x, acc[r][0]);
            acc[r][1] = fmaf(xv.z, wv[2].y, acc[r][1]);
            acc[r][2] = fmaf(xv.z, wv[2].z, acc[r][2]);
            acc[r][3] = fmaf(xv.z, wv[2].w, acc[r][3]);
            acc[r][0] = fmaf(xv.w, wv[3].x, acc[r][0]);
            acc[r][1] = fmaf(xv.w, wv[3].y, acc[r][1]);
            acc[r][2] = fmaf(xv.w, wv[3].z, acc[r][2]);
            acc[r][3] = fmaf(xv.w, wv[3].w, acc[r][3]);
        }
    }
#pragma unroll
    for (int r = 0; r < 4; r++) {
        int row = row0 + 4 * ty + r;
        if (row < n) {
            float sc = scale[row];
            uint2 o;
            o.x = h22u(__floats2half2_rn(acc[r][0] * sc, acc[r][1] * sc));
            o.y = h22u(__floats2half2_rn(acc[r][2] * sc, acc[r][3] * sc));
            *(uint2*)&P[(size_t)row * 64 + 4 * tx] = o;
        }
    }
}

// ---------------- fused gather + relu/norms + next-layer GEMM (16 lanes/node) -------
// 16 lanes per node, uint2 (8B) row slices: deg<=16 nodes finish in ONE dependent
// {csr load -> shfl -> row load} chain (E[iters] 1.63 -> 1.04 vs 8-lane). Index
// prefetch overlaps the next chunk's csr load with accumulation. h kept in registers;
// phase 2 via 64 statically-indexed __shfl (no barrier, no LDS conflicts).
__global__ __launch_bounds__(256) void gather_gemm_kernel(
    const uint4* __restrict__ P4, const int* __restrict__ csr,
    const int* __restrict__ rowbeg, const int* __restrict__ rowend,
    const float* __restrict__ in_norm, const float* __restrict__ out_norm,
    const float* __restrict__ bias, const float* __restrict__ W,
    __half* __restrict__ Pout, int n) {
    __shared__ float Ws[64 * 64];   // 16 KB next-layer weights
    int tid = threadIdx.x;
    {
        const float4* W4 = (const float4*)W;
        float4* Ws4 = (float4*)Ws;
#pragma unroll
        for (int i = 0; i < 4; i++) Ws4[tid + 256 * i] = W4[tid + 256 * i];
    }
    __syncthreads();                // the only barrier

    int g = tid & 15;               // lane within 16-lane node group
    int base_lane = tid & 48;       // group's first lane within the wave
    int v = (int)blockIdx.x * 16 + (tid >> 4);
    if (v >= n) return;             // whole group exits together (same v)

    const uint2* P2 = (const uint2*)P4;
    int begin = rowbeg[v];
    int end = rowend[v];
    float a0 = 0.f, a1 = 0.f, a2 = 0.f, a3 = 0.f;

    int jl = (begin + g < end) ? csr[begin + g] : -1;
    for (int e = begin; e < end; ) {
        int js[16];
#pragma unroll
        for (int k = 0; k < 16; k++) js[k] = __shfl(jl, base_lane + k, 64);
        uint2 t[16];
#pragma unroll
        for (int k = 0; k < 16; k++) {
            t[k] = make_uint2(0u, 0u);
            if (js[k] >= 0) t[k] = P2[(size_t)js[k] * 16 + g];
        }
        e += 16;
        jl = (e + g < end) ? csr[e + g] : -1;     // prefetch next chunk's index
#pragma unroll
        for (int k = 0; k < 16; k++) {
            float2 f0 = __half22float2(u2h2(t[k].x));
            float2 f1 = __half22float2(u2h2(t[k].y));
            a0 += f0.x; a1 += f0.y; a2 += f1.x; a3 += f1.y;
        }
    }
    float inv = in_norm[v];
    float sc = out_norm[v];
    float4 bq = ((const float4*)bias)[g];
    float hr0 = fmaxf(fmaf(a0, inv, bq.x), 0.f) * sc;
    float hr1 = fmaxf(fmaf(a1, inv, bq.y), 0.f) * sc;
    float hr2 = fmaxf(fmaf(a2, inv, bq.z), 0.f) * sc;
    float hr3 = fmaxf(fmaf(a3, inv, bq.w), 0.f) * sc;

    // phase 2: lane computes output feats [4g, 4g+4); h[4gp+ip] = shfl(hr[ip], gp).
    // Ws reads: 16 distinct addrs @ 16B stride spanning 256B -> 2-way (free).
    float o0 = 0.f, o1 = 0.f, o2 = 0.f, o3 = 0.f;
#pragma unroll
    for (int gp = 0; gp < 16; gp++) {
        float h0 = __shfl(hr0, base_lane + gp, 64);
        float h1 = __shfl(hr1, base_lane + gp, 64);
        float h2 = __shfl(hr2, base_lane + gp, 64);
        float h3 = __shfl(hr3, base_lane + gp, 64);
        const float* wr = &Ws[(4 * gp) * 64 + 4 * g];
        float4 w0 = *(const float4*)(wr);
        float4 w1 = *(const float4*)(wr + 64);
        float4 w2 = *(const float4*)(wr + 128);
        float4 w3 = *(const float4*)(wr + 192);
        o0 = fmaf(h0, w0.x, o0); o1 = fmaf(h0, w0.y, o1);
        o2 = fmaf(h0, w0.z, o2); o3 = fmaf(h0, w0.w, o3);
        o0 = fmaf(h1, w1.x, o0); o1 = fmaf(h1, w1.y, o1);
        o2 = fmaf(h1, w1.z, o2); o3 = fmaf(h1, w1.w, o3);
        o0 = fmaf(h2, w2.x, o0); o1 = fmaf(h2, w2.y, o1);
        o2 = fmaf(h2, w2.z, o2); o3 = fmaf(h2, w2.w, o3);
        o0 = fmaf(h3, w3.x, o0); o1 = fmaf(h3, w3.y, o1);
        o2 = fmaf(h3, w3.z, o2); o3 = fmaf(h3, w3.w, o3);
    }
    uint2 t;
    t.x = h22u(__floats2half2_rn(o0, o1));
    t.y = h22u(__floats2half2_rn(o2, o3));
    ((uint2*)Pout)[(size_t)v * 16 + g] = t;       // coalesced 8B/lane, 128B/group
}

// ---------------- final gather (no relu, fp32 out; 16 lanes/node) ----------------
__global__ __launch_bounds__(256) void gather_kernel(
    const uint4* __restrict__ P4, const int* __restrict__ csr,
    const int* __restrict__ rowbeg, const int* __restrict__ rowend,
    const float* __restrict__ in_norm, const float* __restrict__ bias,
    float4* __restrict__ out4, int n) {
    int tid = threadIdx.x;
    int g = tid & 15;
    int base_lane = tid & 48;
    int v = (int)blockIdx.x * 16 + (tid >> 4);
    if (v >= n) return;

    const uint2* P2 = (const uint2*)P4;
    int begin = rowbeg[v];
    int end = rowend[v];
    float a0 = 0.f, a1 = 0.f, a2 = 0.f, a3 = 0.f;

    int jl = (begin + g < end) ? csr[begin + g] : -1;
    for (int e = begin; e < end; ) {
        int js[16];
#pragma unroll
        for (int k = 0; k < 16; k++) js[k] = __shfl(jl, base_lane + k, 64);
        uint2 t[16];
#pragma unroll
        for (int k = 0; k < 16; k++) {
            t[k] = make_uint2(0u, 0u);
            if (js[k] >= 0) t[k] = P2[(size_t)js[k] * 16 + g];
        }
        e += 16;
        jl = (e + g < end) ? csr[e + g] : -1;
#pragma unroll
        for (int k = 0; k < 16; k++) {
            float2 f0 = __half22float2(u2h2(t[k].x));
            float2 f1 = __half22float2(u2h2(t[k].y));
            a0 += f0.x; a1 += f0.y; a2 += f1.x; a3 += f1.y;
        }
    }
    float inv = in_norm[v];
    float4 bq = ((const float4*)bias)[g];
    float4 o;
    o.x = fmaf(a0, inv, bq.x);
    o.y = fmaf(a1, inv, bq.y);
    o.z = fmaf(a2, inv, bq.z);
    o.w = fmaf(a3, inv, bq.w);
    out4[(size_t)v * 16 + g] = o;                  // 16B/lane, 256B/group
}

// ---------------- launch ----------------

extern "C" void kernel_launch(void* const* d_in, const int* in_sizes, int n_in,
                              void* d_out, int out_size, void* d_ws, size_t ws_size,
                              hipStream_t stream) {
    const float* x  = (const float*)d_in[0];
    const int* src  = (const int*)d_in[1];
    const int* dst  = (const int*)d_in[2];
    const float* W1 = (const float*)d_in[3];
    const float* b1 = (const float*)d_in[4];
    const float* W2 = (const float*)d_in[5];
    const float* b2 = (const float*)d_in[6];
    const float* W3 = (const float*)d_in[7];
    const float* b3 = (const float*)d_in[8];

    const int N = in_sizes[0] / D;
    const int E = in_sizes[1];
    const int nb = (N + SZ - 1) / SZ;     // 196 buckets
    const int hb = (E + EPB - 1) / EPB;   // 489 scatter blocks

    char* ws = (char*)d_ws;
    size_t off = 0;
    auto alloc = [&](size_t bytes) -> void* {
        void* p = (void*)(ws + off);
        off += (bytes + 15) & ~(size_t)15;
        return p;
    };
    int* gcntD = (int*)alloc(256 * 4);   // contiguous with gcntS: one memset
    int* gcntS = (int*)alloc(256 * 4);
    unsigned* packD       = (unsigned*)alloc((size_t)nb * CAPB * 4);
    unsigned short* packS = (unsigned short*)alloc((size_t)nb * CAPB * 2);
    int* csr     = (int*)alloc((size_t)nb * CAPB * 4);
    int* rowbeg  = (int*)alloc((size_t)N * 4);
    int* rowend  = (int*)alloc((size_t)N * 4);
    float* innrm = (float*)alloc((size_t)N * 4);
    float* outnrm= (float*)alloc((size_t)N * 4);
    __half* bufPa = (__half*)alloc((size_t)N * D * 2);  // fp16 transformed feats
    __half* bufPb = (__half*)alloc((size_t)N * D * 2);  // ping-pong partner

    const int gemmb = (N + 63) / 64;             // 64-row LDS tiles
    const int sgrid = (N + 15) / 16;             // 16 nodes/block (16 lanes/node)

    hipMemsetAsync(gcntD, 0, 2 * 256 * sizeof(int), stream);

    // A: partition edges into per-bucket regions
    scatter_kernel<<<hb, 256, 0, stream>>>(src, dst, gcntD, gcntS,
                                           packD, packS, E, nb);
    // B: exact CSR + rowbeg/rowend + both norms, all coalesced
    build_kernel<<<2 * nb, 256, 0, stream>>>(packD, packS, gcntD, gcntS, csr,
                                             rowbeg, rowend, innrm, outnrm, N, nb);

    // layer 1: P1 = half(out_norm * (X @ W1)) — scale fused into GEMM epilogue
    gemm_kernel<<<gemmb, 256, 0, stream>>>(x, W1, outnrm, bufPa, N);
    // gather1 + relu/norm + @W2 fused -> P2 (fp16)
    gather_gemm_kernel<<<sgrid, 256, 0, stream>>>((const uint4*)bufPa, csr, rowbeg,
                                                  rowend, innrm, outnrm, b1, W2,
                                                  bufPb, N);
    // gather2 + relu/norm + @W3 fused -> P3 (fp16)
    gather_gemm_kernel<<<sgrid, 256, 0, stream>>>((const uint4*)bufPb, csr, rowbeg,
                                                  rowend, innrm, outnrm, b2, W3,
                                                  bufPa, N);
    // final gather: plain epilogue, fp32 out
    gather_kernel<<<sgrid, 256, 0, stream>>>((const uint4*)bufPa, csr, rowbeg,
                                             rowend, innrm, b3, (float4*)d_out, N);
}

// Round 8
// 226.468 us; speedup vs baseline: 1.0593x; 1.0593x over previous
//
#include <hip/hip_runtime.h>
#include <hip/hip_fp16.h>

#define D 64
#define SZ 512           // nodes per radix bucket (dst>>9 / src>>9)
#define EPB 2048         // edges per scatter block (8/thread, register-held)
#define CAPB 8192        // slots per bucket region; Binom(1e6,1/196) max ~5500 << 8192
// Assumes N <= 131072 (src fits 17 bits, nb <= 256). Harness: N=100000, E=1000000.

static __device__ __forceinline__ __half2 u2h2(unsigned u) {
    union { unsigned u; __half2 h; } c; c.u = u; return c.h;
}
static __device__ __forceinline__ unsigned h22u(__half2 h) {
    union { __half2 h; unsigned u; } c; c.h = h; return c.u;
}

// ---------------- A: bucket-partition edges. 8 edges/thread in REGISTERS (no LDS
// stash -> 6KB LDS), int4-vectorized edge loads. Global atomics only at reserve:
// 2 per (block,bucket). Bucket b owns [b*CAPB, (b+1)*CAPB).
__global__ __launch_bounds__(256) void scatter_kernel(
    const int* __restrict__ src, const int* __restrict__ dst,
    int* __restrict__ gcntD, int* __restrict__ gcntS,
    unsigned* __restrict__ packD, unsigned short* __restrict__ packS,
    int E, int nb) {
    int tid = threadIdx.x;
    __shared__ int hD[256], hS[256], baseD[256], baseS[256], curD[256], curS[256];
    hD[tid] = 0; hS[tid] = 0; curD[tid] = 0; curS[tid] = 0;
    __syncthreads();
    int base = (int)blockIdx.x * EPB + 8 * tid;
    int s0,s1,s2,s3,s4,s5,s6,s7, d0,d1,d2,d3,d4,d5,d6,d7;
    if (base + 8 <= E) {
        int4 a = *(const int4*)&src[base], b = *(const int4*)&src[base + 4];
        s0=a.x; s1=a.y; s2=a.z; s3=a.w; s4=b.x; s5=b.y; s6=b.z; s7=b.w;
        a = *(const int4*)&dst[base]; b = *(const int4*)&dst[base + 4];
        d0=a.x; d1=a.y; d2=a.z; d3=a.w; d4=b.x; d5=b.y; d6=b.z; d7=b.w;
    } else {
        s0=s1=s2=s3=s4=s5=s6=s7=-1; d0=d1=d2=d3=d4=d5=d6=d7=0;
        if (base + 0 < E) { s0 = src[base + 0]; d0 = dst[base + 0]; }
        if (base + 1 < E) { s1 = src[base + 1]; d1 = dst[base + 1]; }
        if (base + 2 < E) { s2 = src[base + 2]; d2 = dst[base + 2]; }
        if (base + 3 < E) { s3 = src[base + 3]; d3 = dst[base + 3]; }
        if (base + 4 < E) { s4 = src[base + 4]; d4 = dst[base + 4]; }
        if (base + 5 < E) { s5 = src[base + 5]; d5 = dst[base + 5]; }
        if (base + 6 < E) { s6 = src[base + 6]; d6 = dst[base + 6]; }
        if (base + 7 < E) { s7 = src[base + 7]; d7 = dst[base + 7]; }
    }
#define HIST(S, Dd) if (S >= 0) { atomicAdd(&hD[Dd >> 9], 1); atomicAdd(&hS[S >> 9], 1); }
    HIST(s0,d0) HIST(s1,d1) HIST(s2,d2) HIST(s3,d3)
    HIST(s4,d4) HIST(s5,d5) HIST(s6,d6) HIST(s7,d7)
#undef HIST
    __syncthreads();
    if (tid < nb) {
        int c = hD[tid];
        baseD[tid] = tid * CAPB + (c ? atomicAdd(&gcntD[tid], c) : 0);
        c = hS[tid];
        baseS[tid] = tid * CAPB + (c ? atomicAdd(&gcntS[tid], c) : 0);
    }
    __syncthreads();
#define SCAT(S, Dd) if (S >= 0) { \
        int bd = Dd >> 9, bs_ = S >> 9; \
        int ld = atomicAdd(&curD[bd], 1); \
        int ls = atomicAdd(&curS[bs_], 1); \
        packD[baseD[bd] + ld] = ((unsigned)S << 9) | (unsigned)(Dd & 511); \
        packS[baseS[bs_] + ls] = (unsigned short)(S & 511); }
    SCAT(s0,d0) SCAT(s1,d1) SCAT(s2,d2) SCAT(s3,d3)
    SCAT(s4,d4) SCAT(s5,d5) SCAT(s6,d6) SCAT(s7,d7)
#undef SCAT
}

// ---------------- B: per-bucket CSR build + norms (uint4-vectorized passes) --------
// Blocks [0,nb): dst role -> rowbeg/rowend, csr, in_norm. Blocks [nb,2nb): out_norm.
__global__ __launch_bounds__(256) void build_kernel(
    const unsigned* __restrict__ packD, const unsigned short* __restrict__ packS,
    const int* __restrict__ gcntD, const int* __restrict__ gcntS,
    int* __restrict__ csr, int* __restrict__ rowbeg, int* __restrict__ rowend,
    float* __restrict__ in_norm, float* __restrict__ out_norm,
    int n, int nb) {
    int tid = threadIdx.x;
    __shared__ int cnt[512], lptr[512], tmp[256];
    bool roleD = ((int)blockIdx.x < nb);
    int b = roleD ? (int)blockIdx.x : (int)blockIdx.x - nb;
    int bs = b * CAPB;
    int be = bs + (roleD ? gcntD[b] : gcntS[b]);
    cnt[tid] = 0; cnt[tid + 256] = 0;
    __syncthreads();
    if (roleD) {
        for (int i = bs + 4 * tid; i < be; i += 1024) {
            if (i + 4 <= be) {
                uint4 p = *(const uint4*)&packD[i];
                atomicAdd(&cnt[p.x & 511], 1); atomicAdd(&cnt[p.y & 511], 1);
                atomicAdd(&cnt[p.z & 511], 1); atomicAdd(&cnt[p.w & 511], 1);
            } else {
                for (int q = i; q < be; q++) atomicAdd(&cnt[packD[q] & 511], 1);
            }
        }
        __syncthreads();
        // exclusive scan over 512 node counts (pair trick with 256 threads)
        int a0 = cnt[2 * tid], a1 = cnt[2 * tid + 1];
        tmp[tid] = a0 + a1; __syncthreads();
        for (int off = 1; off < 256; off <<= 1) {
            int u = (tid >= off) ? tmp[tid - off] : 0; __syncthreads();
            tmp[tid] += u; __syncthreads();
        }
        int ex = tmp[tid] - (a0 + a1);
        lptr[2 * tid] = ex; lptr[2 * tid + 1] = ex + a0;
        __syncthreads();
        int v0 = b * SZ + tid, v1 = v0 + 256;
        if (v0 < n) {
            rowbeg[v0] = bs + lptr[tid];
            rowend[v0] = bs + lptr[tid] + cnt[tid];
            in_norm[v0] = rsqrtf((float)max(cnt[tid], 1));
        }
        if (v1 < n) {
            rowbeg[v1] = bs + lptr[tid + 256];
            rowend[v1] = bs + lptr[tid + 256] + cnt[tid + 256];
            in_norm[v1] = rsqrtf((float)max(cnt[tid + 256], 1));
        }
        __syncthreads();
        // fill packed CSR: slots via LDS cursor (lptr consumed)
        for (int i = bs + 4 * tid; i < be; i += 1024) {
            if (i + 4 <= be) {
                uint4 p = *(const uint4*)&packD[i];
                int sl;
                sl = atomicAdd(&lptr[p.x & 511], 1); csr[bs + sl] = (int)(p.x >> 9);
                sl = atomicAdd(&lptr[p.y & 511], 1); csr[bs + sl] = (int)(p.y >> 9);
                sl = atomicAdd(&lptr[p.z & 511], 1); csr[bs + sl] = (int)(p.z >> 9);
                sl = atomicAdd(&lptr[p.w & 511], 1); csr[bs + sl] = (int)(p.w >> 9);
            } else {
                for (int q = i; q < be; q++) {
                    unsigned p = packD[q];
                    int sl = atomicAdd(&lptr[p & 511], 1);
                    csr[bs + sl] = (int)(p >> 9);
                }
            }
        }
    } else {
        for (int i = bs + 8 * tid; i < be; i += 2048) {
            if (i + 8 <= be) {
                uint4 p = *(const uint4*)&packS[i];     // 8 ushorts
                atomicAdd(&cnt[p.x & 0xFFFF], 1); atomicAdd(&cnt[p.x >> 16], 1);
                atomicAdd(&cnt[p.y & 0xFFFF], 1); atomicAdd(&cnt[p.y >> 16], 1);
                atomicAdd(&cnt[p.z & 0xFFFF], 1); atomicAdd(&cnt[p.z >> 16], 1);
                atomicAdd(&cnt[p.w & 0xFFFF], 1); atomicAdd(&cnt[p.w >> 16], 1);
            } else {
                for (int q = i; q < be; q++) atomicAdd(&cnt[packS[q]], 1);
            }
        }
        __syncthreads();
        int v0 = b * SZ + tid, v1 = v0 + 256;
        if (v0 < n) out_norm[v0] = rsqrtf((float)max(cnt[tid], 1));
        if (v1 < n) out_norm[v1] = rsqrtf((float)max(cnt[tid + 256], 1));
    }
}

// ---------------- GEMM: Y = half(scale * (X @ W)), 64x64 LDS tile, 4x4/thread -------
// Xs: 16B-chunk XOR swizzle (chunk kq of row r at Xs[r*64 + ((kq^(r&15))<<2)]).
// __launch_bounds__(256,4): cap VGPR (round-2 lesson: uncapped -> 244 VGPR, 9% occ).
__global__ __launch_bounds__(256, 4) void gemm_kernel(
    const float* __restrict__ X, const float* __restrict__ W,
    const float* __restrict__ scale, __half* __restrict__ P, int n) {
    __shared__ float Ws[64 * 64];
    __shared__ float Xs[64 * 64];
    int tid = threadIdx.x;
    int row0 = (int)blockIdx.x * 64;
    if (row0 >= n) return;
    {
        const float4* W4 = (const float4*)W;
        float4* Ws4 = (float4*)Ws;
#pragma unroll
        for (int i = 0; i < 4; i++) Ws4[tid + 256 * i] = W4[tid + 256 * i];
    }
    {
#pragma unroll
        for (int i = 0; i < 4; i++) {
            int idx = tid + 256 * i;          // 0..1023 = 64 rows x 16 chunks
            int r = idx >> 4, kq = idx & 15;
            float4 v = make_float4(0.f, 0.f, 0.f, 0.f);
            int row = row0 + r;
            if (row < n) v = ((const float4*)X)[(size_t)row * 16 + kq];
            *(float4*)&Xs[r * 64 + ((kq ^ (r & 15)) << 2)] = v;
        }
    }
    __syncthreads();

    int tx = tid & 15, ty = tid >> 4;
    float acc[4][4] = {};
#pragma unroll 4
    for (int kc = 0; kc < 16; kc++) {
        float4 wv[4];
#pragma unroll
        for (int j = 0; j < 4; j++) wv[j] = *(float4*)&Ws[(4 * kc + j) * 64 + 4 * tx];
#pragma unroll
        for (int r = 0; r < 4; r++) {
            int row = 4 * ty + r;
            float4 xv = *(float4*)&Xs[row * 64 + ((kc ^ (row & 15)) << 2)];
            acc[r][0] = fmaf(xv.x, wv[0].x, acc[r][0]);
            acc[r][1] = fmaf(xv.x, wv[0].y, acc[r][1]);
            acc[r][2] = fmaf(xv.x, wv[0].z, acc[r][2]);
            acc[r][3] = fmaf(xv.x, wv[0].w, acc[r][3]);
            acc[r][0] = fmaf(xv.y, wv[1].x, acc[r][0]);
            acc[r][1] = fmaf(xv.y, wv[1].y, acc[r][1]);
            acc[r][2] = fmaf(xv.y, wv[1].z, acc[r][2]);
            acc[r][3] = fmaf(xv.y, wv[1].w, acc[r][3]);
            acc[r][0] = fmaf(xv.z, wv[2].x, acc[r][0]);
            acc[r][1] = fmaf(xv.z, wv[2].y, acc[r][1]);
            acc[r][2] = fmaf(xv.z, wv[2].z, acc[r][2]);
            acc[r][3] = fmaf(xv.z, wv[2].w, acc[r][3]);
            acc[r][0] = fmaf(xv.w, wv[3].x, acc[r][0]);
            acc[r][1] = fmaf(xv.w, wv[3].y, acc[r][1]);
            acc[r][2] = fmaf(xv.w, wv[3].z, acc[r][2]);
            acc[r][3] = fmaf(xv.w, wv[3].w, acc[r][3]);
        }
    }
#pragma unroll
    for (int r = 0; r < 4; r++) {
        int row = row0 + 4 * ty + r;
        if (row < n) {
            float sc = scale[row];
            uint2 o;
            o.x = h22u(__floats2half2_rn(acc[r][0] * sc, acc[r][1] * sc));
            o.y = h22u(__floats2half2_rn(acc[r][2] * sc, acc[r][3] * sc));
            *(uint2*)&P[(size_t)row * 64 + 4 * tx] = o;
        }
    }
}

// ---------------- fused gather + relu/norms + next-layer GEMM (8 lanes/node) --------
// Round-6 proven structure (round-7 lesson: 16-lane uint2 slices double the load
// instruction count for the same bytes -> regression; gather is service-rate-bound,
// not chain-latency-bound). Full 128B rows as uint4/lane; h in registers; phase 2
// via 64 statically-indexed __shfl (no barrier, no LDS conflicts). LDS 16KB.
__global__ __launch_bounds__(256) void gather_gemm_kernel(
    const uint4* __restrict__ P4, const int* __restrict__ csr,
    const int* __restrict__ rowbeg, const int* __restrict__ rowend,
    const float* __restrict__ in_norm, const float* __restrict__ out_norm,
    const float* __restrict__ bias, const float* __restrict__ W,
    __half* __restrict__ Pout, int n) {
    __shared__ float Ws[64 * 64];   // 16 KB next-layer weights
    int tid = threadIdx.x;
    {
        const float4* W4 = (const float4*)W;
        float4* Ws4 = (float4*)Ws;
#pragma unroll
        for (int i = 0; i < 4; i++) Ws4[tid + 256 * i] = W4[tid + 256 * i];
    }
    __syncthreads();                // the only barrier

    int g = tid & 7;
    int base_lane = tid & 56;
    int v = (int)blockIdx.x * 32 + (tid >> 3);
    if (v >= n) return;             // whole 8-lane group exits together (same v)

    int begin = rowbeg[v];
    int end = rowend[v];
    float al0 = 0.f, al1 = 0.f, al2 = 0.f, al3 = 0.f;
    float ah0 = 0.f, ah1 = 0.f, ah2 = 0.f, ah3 = 0.f;
    for (int e = begin; e < end; e += 8) {
        int ee = e + g;
        int jl = (ee < end) ? csr[ee] : -1;       // coalesced idx read
        int js[8];
#pragma unroll
        for (int k = 0; k < 8; k++) js[k] = __shfl(jl, base_lane + k, 64);
        uint4 t[8];
#pragma unroll
        for (int k = 0; k < 8; k++) {
            t[k] = make_uint4(0u, 0u, 0u, 0u);
            if (js[k] >= 0) t[k] = P4[(size_t)js[k] * 8 + g];
        }
#pragma unroll
        for (int k = 0; k < 8; k++) {
            float2 f0 = __half22float2(u2h2(t[k].x));
            float2 f1 = __half22float2(u2h2(t[k].y));
            float2 f2 = __half22float2(u2h2(t[k].z));
            float2 f3 = __half22float2(u2h2(t[k].w));
            al0 += f0.x; al1 += f0.y; al2 += f1.x; al3 += f1.y;
            ah0 += f2.x; ah1 += f2.y; ah2 += f3.x; ah3 += f3.y;
        }
    }
    float inv = in_norm[v];
    float sc = out_norm[v];
    float4 blo = ((const float4*)bias)[2 * g];
    float4 bhi = ((const float4*)bias)[2 * g + 1];
    float hr[8];
    hr[0] = fmaxf(fmaf(al0, inv, blo.x), 0.f) * sc;
    hr[1] = fmaxf(fmaf(al1, inv, blo.y), 0.f) * sc;
    hr[2] = fmaxf(fmaf(al2, inv, blo.z), 0.f) * sc;
    hr[3] = fmaxf(fmaf(al3, inv, blo.w), 0.f) * sc;
    hr[4] = fmaxf(fmaf(ah0, inv, bhi.x), 0.f) * sc;
    hr[5] = fmaxf(fmaf(ah1, inv, bhi.y), 0.f) * sc;
    hr[6] = fmaxf(fmaf(ah2, inv, bhi.z), 0.f) * sc;
    hr[7] = fmaxf(fmaf(ah3, inv, bhi.w), 0.f) * sc;

    // phase 2: this lane computes output feats [8g, 8g+8) for node v.
    // Ws reads: 8 distinct addrs @ 32B stride per instruction -> 2-way (free).
    float o[8];
#pragma unroll
    for (int i = 0; i < 8; i++) o[i] = 0.f;
#pragma unroll
    for (int gp = 0; gp < 8; gp++) {
#pragma unroll
        for (int ip = 0; ip < 8; ip++) {
            float hk = __shfl(hr[ip], base_lane + gp, 64);   // static reg index
            const float* wrow = &Ws[(8 * gp + ip) * 64 + 8 * g];
            float4 w0 = *(const float4*)wrow;
            float4 w1 = *(const float4*)(wrow + 4);
            o[0] = fmaf(hk, w0.x, o[0]); o[1] = fmaf(hk, w0.y, o[1]);
            o[2] = fmaf(hk, w0.z, o[2]); o[3] = fmaf(hk, w0.w, o[3]);
            o[4] = fmaf(hk, w1.x, o[4]); o[5] = fmaf(hk, w1.y, o[5]);
            o[6] = fmaf(hk, w1.z, o[6]); o[7] = fmaf(hk, w1.w, o[7]);
        }
    }
    uint4 t;
    t.x = h22u(__floats2half2_rn(o[0], o[1]));
    t.y = h22u(__floats2half2_rn(o[2], o[3]));
    t.z = h22u(__floats2half2_rn(o[4], o[5]));
    t.w = h22u(__floats2half2_rn(o[6], o[7]));
    ((uint4*)Pout)[(size_t)v * 8 + g] = t;                   // coalesced 16B/lane
}

// ---------------- final gather (no relu, fp32 out; 8 lanes/node) ----------------
__global__ __launch_bounds__(256) void gather_kernel(
    const uint4* __restrict__ P4, const int* __restrict__ csr,
    const int* __restrict__ rowbeg, const int* __restrict__ rowend,
    const float* __restrict__ in_norm, const float* __restrict__ bias,
    float4* __restrict__ out4, int n) {
    int tid = threadIdx.x;
    int g = tid & 7;
    int base_lane = tid & 56;
    int v = blockIdx.x * 32 + (tid >> 3);
    if (v >= n) return;

    int begin = rowbeg[v];
    int end = rowend[v];
    float inv = in_norm[v];
    float4 blo = ((const float4*)bias)[2 * g];
    float4 bhi = ((const float4*)bias)[2 * g + 1];

    float al0 = 0.f, al1 = 0.f, al2 = 0.f, al3 = 0.f;
    float ah0 = 0.f, ah1 = 0.f, ah2 = 0.f, ah3 = 0.f;

    for (int e = begin; e < end; e += 8) {
        int ee = e + g;
        int jl = (ee < end) ? csr[ee] : -1;
        int js[8];
#pragma unroll
        for (int k = 0; k < 8; k++) js[k] = __shfl(jl, base_lane + k, 64);
        uint4 t[8];
#pragma unroll
        for (int k = 0; k < 8; k++) {
            t[k] = make_uint4(0u, 0u, 0u, 0u);
            if (js[k] >= 0) t[k] = P4[(size_t)js[k] * 8 + g];
        }
#pragma unroll
        for (int k = 0; k < 8; k++) {
            float2 f0 = __half22float2(u2h2(t[k].x));
            float2 f1 = __half22float2(u2h2(t[k].y));
            float2 f2 = __half22float2(u2h2(t[k].z));
            float2 f3 = __half22float2(u2h2(t[k].w));
            al0 += f0.x; al1 += f0.y; al2 += f1.x; al3 += f1.y;
            ah0 += f2.x; ah1 += f2.y; ah2 += f3.x; ah3 += f3.y;
        }
    }

    float4 o0, o1;
    o0.x = fmaf(al0, inv, blo.x); o0.y = fmaf(al1, inv, blo.y);
    o0.z = fmaf(al2, inv, blo.z); o0.w = fmaf(al3, inv, blo.w);
    o1.x = fmaf(ah0, inv, bhi.x); o1.y = fmaf(ah1, inv, bhi.y);
    o1.z = fmaf(ah2, inv, bhi.z); o1.w = fmaf(ah3, inv, bhi.w);
    out4[(size_t)v * 16 + 2 * g] = o0;
    out4[(size_t)v * 16 + 2 * g + 1] = o1;
}

// ---------------- launch ----------------

extern "C" void kernel_launch(void* const* d_in, const int* in_sizes, int n_in,
                              void* d_out, int out_size, void* d_ws, size_t ws_size,
                              hipStream_t stream) {
    const float* x  = (const float*)d_in[0];
    const int* src  = (const int*)d_in[1];
    const int* dst  = (const int*)d_in[2];
    const float* W1 = (const float*)d_in[3];
    const float* b1 = (const float*)d_in[4];
    const float* W2 = (const float*)d_in[5];
    const float* b2 = (const float*)d_in[6];
    const float* W3 = (const float*)d_in[7];
    const float* b3 = (const float*)d_in[8];

    const int N = in_sizes[0] / D;
    const int E = in_sizes[1];
    const int nb = (N + SZ - 1) / SZ;     // 196 buckets
    const int hb = (E + EPB - 1) / EPB;   // 489 scatter blocks

    char* ws = (char*)d_ws;
    size_t off = 0;
    auto alloc = [&](size_t bytes) -> void* {
        void* p = (void*)(ws + off);
        off += (bytes + 15) & ~(size_t)15;
        return p;
    };
    int* gcntD = (int*)alloc(256 * 4);   // contiguous with gcntS: one memset
    int* gcntS = (int*)alloc(256 * 4);
    unsigned* packD       = (unsigned*)alloc((size_t)nb * CAPB * 4);
    unsigned short* packS = (unsigned short*)alloc((size_t)nb * CAPB * 2);
    int* csr     = (int*)alloc((size_t)nb * CAPB * 4);
    int* rowbeg  = (int*)alloc((size_t)N * 4);
    int* rowend  = (int*)alloc((size_t)N * 4);
    float* innrm = (float*)alloc((size_t)N * 4);
    float* outnrm= (float*)alloc((size_t)N * 4);
    __half* bufPa = (__half*)alloc((size_t)N * D * 2);  // fp16 transformed feats
    __half* bufPb = (__half*)alloc((size_t)N * D * 2);  // ping-pong partner

    const int gemmb = (N + 63) / 64;             // 64-row LDS tiles
    const int sgrid = (N + 31) / 32;             // 32 nodes/block (8 lanes/node)

    hipMemsetAsync(gcntD, 0, 2 * 256 * sizeof(int), stream);

    // A: partition edges into per-bucket regions
    scatter_kernel<<<hb, 256, 0, stream>>>(src, dst, gcntD, gcntS,
                                           packD, packS, E, nb);
    // B: exact CSR + rowbeg/rowend + both norms, all coalesced
    build_kernel<<<2 * nb, 256, 0, stream>>>(packD, packS, gcntD, gcntS, csr,
                                             rowbeg, rowend, innrm, outnrm, N, nb);

    // layer 1: P1 = half(out_norm * (X @ W1)) — scale fused into GEMM epilogue
    gemm_kernel<<<gemmb, 256, 0, stream>>>(x, W1, outnrm, bufPa, N);
    // gather1 + relu/norm + @W2 fused -> P2 (fp16)
    gather_gemm_kernel<<<sgrid, 256, 0, stream>>>((const uint4*)bufPa, csr, rowbeg,
                                                  rowend, innrm, outnrm, b1, W2,
                                                  bufPb, N);
    // gather2 + relu/norm + @W3 fused -> P3 (fp16)
    gather_gemm_kernel<<<sgrid, 256, 0, stream>>>((const uint4*)bufPb, csr, rowbeg,
                                                  rowend, innrm, outnrm, b2, W3,
                                                  bufPa, N);
    // final gather: plain epilogue, fp32 out
    gather_kernel<<<sgrid, 256, 0, stream>>>((const uint4*)bufPa, csr, rowbeg,
                                             rowend, innrm, b3, (float4*)d_out, N);
}